// Round 9
// baseline (100.642 us; speedup 1.0000x reference)
//
#include <hip/hip_runtime.h>

#define NC 256
#define NB 32
#define HW 4096
#define HW4 1024
#define KC 768   // KERNEL * NC
#define BN_EPS 1e-5f
#define CG 64    // channels per fused block

typedef float f32x4 __attribute__((ext_vector_type(4)));

// ---------------- Kernel 1: global average pool per (b,c) ----------------
__global__ __launch_bounds__(256) void gap_kernel(const float* __restrict__ x,
                                                  float* __restrict__ g) {
    const int bc = blockIdx.x;
    const f32x4* xp = reinterpret_cast<const f32x4*>(x) + (size_t)bc * HW4;
    const int t = threadIdx.x;
    float s = 0.f;
#pragma unroll
    for (int k = 0; k < 4; ++k) {
        f32x4 v = xp[t + k * 256];
        s += (v.x + v.y) + (v.z + v.w);
    }
#pragma unroll
    for (int off = 32; off > 0; off >>= 1) s += __shfl_down(s, off, 64);
    __shared__ float warp_sums[4];
    const int lane = t & 63, w = t >> 6;
    if (lane == 0) warp_sums[w] = s;
    __syncthreads();
    if (t == 0) {
        float tot = (warp_sums[0] + warp_sums[1]) + (warp_sums[2] + warp_sums[3]);
        g[bc] = tot * (1.0f / HW);
    }
}

// ---------------- Kernel 2 (fused): taps + dynamic filter + affine ----------------
// 256 blocks: (b, 64-channel group, plane-half). Phase B: block computes its
// own 192 taps from LDS-staged g[b,:] (cw rows are L2-resident, 768KB total).
// Phase C: sliding-window apply, 2 f32x4 columns/thread, 8KB-linear streams.
__global__ __launch_bounds__(256) void fused_kernel(
    const float* __restrict__ x, const float* __restrict__ g,
    const float* __restrict__ cw,
    const float* __restrict__ bn_w, const float* __restrict__ bn_b,
    const float* __restrict__ bn_m, const float* __restrict__ bn_v,
    const float* __restrict__ gamma, const float* __restrict__ beta,
    float* __restrict__ out) {
    const int bid  = blockIdx.x;        // 256
    const int half = bid & 1;
    const int cgp  = (bid >> 1) & 3;
    const int b    = bid >> 3;
    const int t    = threadIdx.x;
    const int wave = t >> 6, lane = t & 63;
    const int c0   = cgp * CG;

    // ---- stage g[b,:] ----
    __shared__ float gs[NC];
    gs[t] = g[b * NC + t];
    // ---- stage gamma/beta for this channel group ----
    __shared__ float ga_s[CG], be_s[CG];
    __shared__ float f_s[3][CG];
    __syncthreads();

    if (t < CG)            ga_s[t] = gamma[c0 + t];
    else if (t < 2 * CG)   be_s[t - CG] = beta[c0 + t - CG];

    // ---- Phase B: 192 taps, 48 rows per wave ----
    {
        const f32x4 gv = reinterpret_cast<const f32x4*>(gs)[lane];
#pragma unroll
        for (int r = 0; r < 48; ++r) {
            const int rl = wave * 48 + r;          // 0..191
            const int k  = rl >> 6;
            const int ci = rl & 63;
            const int j  = k * NC + c0 + ci;
            const f32x4 wv = reinterpret_cast<const f32x4*>(cw + (size_t)j * NC)[lane];
            float s = fmaf(gv.x, wv.x, fmaf(gv.y, wv.y, fmaf(gv.z, wv.z, gv.w * wv.w)));
#pragma unroll
            for (int off = 32; off > 0; off >>= 1) s += __shfl_down(s, off, 64);
            if (lane == 0) {
                const float yn = (s - bn_m[j]) * rsqrtf(bn_v[j] + BN_EPS) * bn_w[j] + bn_b[j];
                f_s[k][ci] = tanhf(yn);
            }
        }
    }
    __syncthreads();

    // ---- Phase C: sliding-window apply over CG channels, half plane ----
    const size_t bbase = (size_t)b * NC * HW4;
    const f32x4* x4 = reinterpret_cast<const f32x4*>(x) + bbase;
    f32x4* o4 = reinterpret_cast<f32x4*>(out) + bbase;
    const int col0 = half * 512 + t;
    const int col1 = col0 + 256;

    f32x4 prv0, prv1, cur0, cur1, nxt0, nxt1;
    cur0 = x4[(size_t)c0 * HW4 + col0];
    cur1 = x4[(size_t)c0 * HW4 + col1];
    nxt0 = x4[(size_t)(c0 + 1) * HW4 + col0];
    nxt1 = x4[(size_t)(c0 + 1) * HW4 + col1];
    if (c0 == 0) { prv0 = nxt0; prv1 = nxt1; }
    else {
        prv0 = x4[(size_t)(c0 - 1) * HW4 + col0];
        prv1 = x4[(size_t)(c0 - 1) * HW4 + col1];
    }

#pragma unroll 4
    for (int ci = 0; ci < CG; ++ci) {
        const int c  = c0 + ci;
        const int cn = (c + 2 < NC) ? (c + 2) : (NC - 1);   // clamped prefetch
        f32x4 nn0 = x4[(size_t)cn * HW4 + col0];
        f32x4 nn1 = x4[(size_t)cn * HW4 + col1];
        const float f0 = f_s[0][ci];
        const float f1 = f_s[1][ci];
        const float f2 = f_s[2][ci];
        const float ga = ga_s[ci];
        const float be = be_s[ci];
        const f32x4 xm0 = (c == 0) ? nxt0 : prv0;        // reflect left
        const f32x4 xm1 = (c == 0) ? nxt1 : prv1;
        const f32x4 xq0 = (c == NC - 1) ? prv0 : nxt0;   // reflect right
        const f32x4 xq1 = (c == NC - 1) ? prv1 : nxt1;
        f32x4 r0, r1;
        r0.x = fmaf(fmaf(f0, xm0.x, fmaf(f1, cur0.x, f2 * xq0.x)), ga, cur0.x * be);
        r0.y = fmaf(fmaf(f0, xm0.y, fmaf(f1, cur0.y, f2 * xq0.y)), ga, cur0.y * be);
        r0.z = fmaf(fmaf(f0, xm0.z, fmaf(f1, cur0.z, f2 * xq0.z)), ga, cur0.z * be);
        r0.w = fmaf(fmaf(f0, xm0.w, fmaf(f1, cur0.w, f2 * xq0.w)), ga, cur0.w * be);
        r1.x = fmaf(fmaf(f0, xm1.x, fmaf(f1, cur1.x, f2 * xq1.x)), ga, cur1.x * be);
        r1.y = fmaf(fmaf(f0, xm1.y, fmaf(f1, cur1.y, f2 * xq1.y)), ga, cur1.y * be);
        r1.z = fmaf(fmaf(f0, xm1.z, fmaf(f1, cur1.z, f2 * xq1.z)), ga, cur1.z * be);
        r1.w = fmaf(fmaf(f0, xm1.w, fmaf(f1, cur1.w, f2 * xq1.w)), ga, cur1.w * be);
        o4[(size_t)c * HW4 + col0] = r0;
        o4[(size_t)c * HW4 + col1] = r1;
        prv0 = cur0; cur0 = nxt0; nxt0 = nn0;
        prv1 = cur1; cur1 = nxt1; nxt1 = nn1;
    }
}

extern "C" void kernel_launch(void* const* d_in, const int* in_sizes, int n_in,
                              void* d_out, int out_size, void* d_ws, size_t ws_size,
                              hipStream_t stream) {
    const float* x     = (const float*)d_in[0];
    const float* cw    = (const float*)d_in[1];
    const float* bn_w  = (const float*)d_in[2];
    const float* bn_b  = (const float*)d_in[3];
    const float* bn_m  = (const float*)d_in[4];
    const float* bn_v  = (const float*)d_in[5];
    const float* gamma = (const float*)d_in[6];
    const float* beta  = (const float*)d_in[7];
    float* out = (float*)d_out;

    float* g = (float*)d_ws;                    // NB*NC floats

    gap_kernel<<<NB * NC, 256, 0, stream>>>(x, g);
    fused_kernel<<<NB * (NC / CG) * 2, 256, 0, stream>>>(
        x, g, cw, bn_w, bn_b, bn_m, bn_v, gamma, beta, out);
}

// Round 10
// 74.556 us; speedup vs baseline: 1.3499x; 1.3499x over previous
//
#include <hip/hip_runtime.h>

#define NC 256
#define NB 32
#define HW 4096
#define HW4 1024
#define KC 768   // KERNEL * NC
#define BN_EPS 1e-5f
#define CG 64    // channels per apply block

typedef float f32x4 __attribute__((ext_vector_type(4)));

// ---------------- Kernel 1: global average pool per (b,c) ----------------
__global__ __launch_bounds__(256) void gap_kernel(const float* __restrict__ x,
                                                  float* __restrict__ g) {
    const int bc = blockIdx.x;
    const f32x4* xp = reinterpret_cast<const f32x4*>(x) + (size_t)bc * HW4;
    const int t = threadIdx.x;
    float s = 0.f;
#pragma unroll
    for (int k = 0; k < 4; ++k) {
        f32x4 v = xp[t + k * 256];
        s += (v.x + v.y) + (v.z + v.w);
    }
#pragma unroll
    for (int off = 32; off > 0; off >>= 1) s += __shfl_down(s, off, 64);
    __shared__ float warp_sums[4];
    const int lane = t & 63, w = t >> 6;
    if (lane == 0) warp_sums[w] = s;
    __syncthreads();
    if (t == 0) {
        float tot = (warp_sums[0] + warp_sums[1]) + (warp_sums[2] + warp_sums[3]);
        g[bc] = tot * (1.0f / HW);
    }
}

// ---------------- Kernel 2: 1x1 conv (768x256 dot) + BN + tanh ----------------
__global__ __launch_bounds__(256) void filt_kernel(const float* __restrict__ g,
                                                   const float* __restrict__ cw,
                                                   const float* __restrict__ bn_w,
                                                   const float* __restrict__ bn_b,
                                                   const float* __restrict__ bn_m,
                                                   const float* __restrict__ bn_v,
                                                   float* __restrict__ f) {
    const int b = blockIdx.y;
    const int t = threadIdx.x;
    __shared__ float gs[NC];
    gs[t] = g[b * NC + t];
    __syncthreads();
    const int wave = t >> 6, lane = t & 63;
    const f32x4 gv = reinterpret_cast<const f32x4*>(gs)[lane];
    const int row0 = blockIdx.x * 32 + wave * 8;
#pragma unroll
    for (int i = 0; i < 8; ++i) {
        const int j = row0 + i;
        const f32x4 wv = reinterpret_cast<const f32x4*>(cw + (size_t)j * NC)[lane];
        float s = fmaf(gv.x, wv.x, fmaf(gv.y, wv.y, fmaf(gv.z, wv.z, gv.w * wv.w)));
#pragma unroll
        for (int off = 32; off > 0; off >>= 1) s += __shfl_down(s, off, 64);
        if (lane == 0) {
            float yn = (s - bn_m[j]) * rsqrtf(bn_v[j] + BN_EPS) * bn_w[j] + bn_b[j];
            f[b * KC + j] = tanhf(yn);
        }
    }
}

// ---------------- Kernel 3: dynamic channel-local filter + affine ----------------
// 256 blocks: (b, 64-ch group, plane-half). 2 f32x4 columns/thread -> 8KB-linear
// streams; halo 2/64 = 3.1%; depth-2 prefetch (5-plane window, ~40 VGPRs).
__global__ __launch_bounds__(256) void apply_kernel(const float* __restrict__ x,
                                                    const float* __restrict__ f,
                                                    const float* __restrict__ gamma,
                                                    const float* __restrict__ beta,
                                                    float* __restrict__ out) {
    const int bid  = blockIdx.x;        // 256
    const int half = bid & 1;
    const int cgp  = (bid >> 1) & 3;
    const int b    = bid >> 3;
    const int t    = threadIdx.x;
    const int c0   = cgp * CG;

    __shared__ float f_s[3][CG];
    __shared__ float ga_s[CG], be_s[CG];
    {
        const float* fb = f + b * KC;
        if (t < 192)      f_s[t >> 6][t & 63] = fb[(t >> 6) * NC + c0 + (t & 63)];
        else              ga_s[t - 192] = gamma[c0 + t - 192];
        if (t < CG)       be_s[t] = beta[c0 + t];
    }

    const size_t bbase = (size_t)b * NC * HW4;
    const f32x4* x4 = reinterpret_cast<const f32x4*>(x) + bbase;
    f32x4* o4 = reinterpret_cast<f32x4*>(out) + bbase;
    const int col0 = half * 512 + t;
    const int col1 = col0 + 256;

    // 5-plane pipeline per column: prv,cur,nxt active; p2,p3 in flight
    f32x4 cur0 = x4[(size_t)c0 * HW4 + col0];
    f32x4 cur1 = x4[(size_t)c0 * HW4 + col1];
    f32x4 nxt0 = x4[(size_t)(c0 + 1) * HW4 + col0];
    f32x4 nxt1 = x4[(size_t)(c0 + 1) * HW4 + col1];
    f32x4 p20  = x4[(size_t)(c0 + 2) * HW4 + col0];
    f32x4 p21  = x4[(size_t)(c0 + 2) * HW4 + col1];
    f32x4 p30  = x4[(size_t)(c0 + 3) * HW4 + col0];
    f32x4 p31  = x4[(size_t)(c0 + 3) * HW4 + col1];
    f32x4 prv0, prv1;
    if (c0 == 0) { prv0 = nxt0; prv1 = nxt1; }
    else {
        prv0 = x4[(size_t)(c0 - 1) * HW4 + col0];
        prv1 = x4[(size_t)(c0 - 1) * HW4 + col1];
    }
    __syncthreads();

#pragma unroll 4
    for (int ci = 0; ci < CG; ++ci) {
        const int c  = c0 + ci;
        const int cn = (c + 4 < NC) ? (c + 4) : (NC - 1);   // clamped prefetch
        f32x4 nn0 = x4[(size_t)cn * HW4 + col0];
        f32x4 nn1 = x4[(size_t)cn * HW4 + col1];
        const float f0 = f_s[0][ci];
        const float f1 = f_s[1][ci];
        const float f2 = f_s[2][ci];
        const float ga = ga_s[ci];
        const float be = be_s[ci];
        const f32x4 xm0 = (c == 0) ? nxt0 : prv0;        // reflect left
        const f32x4 xm1 = (c == 0) ? nxt1 : prv1;
        const f32x4 xq0 = (c == NC - 1) ? prv0 : nxt0;   // reflect right
        const f32x4 xq1 = (c == NC - 1) ? prv1 : nxt1;
        f32x4 r0, r1;
        r0.x = fmaf(fmaf(f0, xm0.x, fmaf(f1, cur0.x, f2 * xq0.x)), ga, cur0.x * be);
        r0.y = fmaf(fmaf(f0, xm0.y, fmaf(f1, cur0.y, f2 * xq0.y)), ga, cur0.y * be);
        r0.z = fmaf(fmaf(f0, xm0.z, fmaf(f1, cur0.z, f2 * xq0.z)), ga, cur0.z * be);
        r0.w = fmaf(fmaf(f0, xm0.w, fmaf(f1, cur0.w, f2 * xq0.w)), ga, cur0.w * be);
        r1.x = fmaf(fmaf(f0, xm1.x, fmaf(f1, cur1.x, f2 * xq1.x)), ga, cur1.x * be);
        r1.y = fmaf(fmaf(f0, xm1.y, fmaf(f1, cur1.y, f2 * xq1.y)), ga, cur1.y * be);
        r1.z = fmaf(fmaf(f0, xm1.z, fmaf(f1, cur1.z, f2 * xq1.z)), ga, cur1.z * be);
        r1.w = fmaf(fmaf(f0, xm1.w, fmaf(f1, cur1.w, f2 * xq1.w)), ga, cur1.w * be);
        o4[(size_t)c * HW4 + col0] = r0;
        o4[(size_t)c * HW4 + col1] = r1;
        prv0 = cur0; cur0 = nxt0; nxt0 = p20; p20 = p30; p30 = nn0;
        prv1 = cur1; cur1 = nxt1; nxt1 = p21; p21 = p31; p31 = nn1;
    }
}

extern "C" void kernel_launch(void* const* d_in, const int* in_sizes, int n_in,
                              void* d_out, int out_size, void* d_ws, size_t ws_size,
                              hipStream_t stream) {
    const float* x     = (const float*)d_in[0];
    const float* cw    = (const float*)d_in[1];
    const float* bn_w  = (const float*)d_in[2];
    const float* bn_b  = (const float*)d_in[3];
    const float* bn_m  = (const float*)d_in[4];
    const float* bn_v  = (const float*)d_in[5];
    const float* gamma = (const float*)d_in[6];
    const float* beta  = (const float*)d_in[7];
    float* out = (float*)d_out;

    float* g = (float*)d_ws;                    // NB*NC floats
    float* f = g + NB * NC;                     // NB*KC floats

    gap_kernel<<<NB * NC, 256, 0, stream>>>(x, g);
    filt_kernel<<<dim3(24, NB), 256, 0, stream>>>(g, cw, bn_w, bn_b, bn_m, bn_v, f);
    apply_kernel<<<NB * (NC / CG) * 2, 256, 0, stream>>>(x, f, gamma, beta, out);
}